// Round 1
// baseline (1170.550 us; speedup 1.0000x reference)
//
#include <hip/hip_runtime.h>
#include <hip/hip_bf16.h>

// y = x @ W_eff^T with W_eff = W_base + 0.5*sum(alpha_i * B_i A_i)
// Split-bf16 (Ootomo) GEMM: y = xh@Wh^T + xh@Wl^T + xl@Wh^T  (error ~1e-4 abs)
//
// ws layout: xh 64MB | xl 64MB | Wh 32MB | Wl 32MB  (192 MB total)

typedef __attribute__((ext_vector_type(8))) short bf16x8;
typedef __attribute__((ext_vector_type(4))) float f32x4;
typedef __attribute__((ext_vector_type(8))) unsigned short u16x8;

#define GLOBAL_LOAD_LDS16(gp, lp)                                                   \
  __builtin_amdgcn_global_load_lds(                                                 \
      (const __attribute__((address_space(1))) unsigned int*)(gp),                  \
      (__attribute__((address_space(3))) unsigned int*)(lp), 16, 0, 0)

__device__ inline unsigned short bf16_rne(float f) {
  unsigned int u = __builtin_bit_cast(unsigned int, f);
  u += 0x7fffu + ((u >> 16) & 1u);
  return (unsigned short)(u >> 16);
}
__device__ inline float bf16_to_f(unsigned short h) {
  unsigned int u = ((unsigned int)h) << 16;
  return __builtin_bit_cast(float, u);
}

// ---------------- kernel 1: split x into hi/lo bf16 ----------------
__global__ __launch_bounds__(256) void split_x(const float* __restrict__ x,
                                               unsigned short* __restrict__ xh,
                                               unsigned short* __restrict__ xl) {
  size_t i = ((size_t)blockIdx.x * 256 + threadIdx.x) * 8;
  float4 v0 = *(const float4*)(x + i);
  float4 v1 = *(const float4*)(x + i + 4);
  float f[8] = {v0.x, v0.y, v0.z, v0.w, v1.x, v1.y, v1.z, v1.w};
  u16x8 vh, vl;
#pragma unroll
  for (int j = 0; j < 8; ++j) {
    unsigned short h = bf16_rne(f[j]);
    vh[j] = h;
    vl[j] = bf16_rne(f[j] - bf16_to_f(h));
  }
  *(u16x8*)(xh + i) = vh;
  *(u16x8*)(xl + i) = vl;
}

// ---------------- kernel 2: fold adapters into W_eff, split hi/lo ----------------
// W_eff[o][d] = W[o][d] + sum_r Bc[o][r] * Acat[r][d],  Bc pre-scaled by 0.5*alpha_i
__global__ __launch_bounds__(256) void fold_w(
    const float* __restrict__ W, const float* __restrict__ A8,
    const float* __restrict__ B8, const float* __restrict__ A16,
    const float* __restrict__ B16, const float* __restrict__ A32,
    const float* __restrict__ B32, const float* __restrict__ alphas,
    unsigned short* __restrict__ Wh, unsigned short* __restrict__ Wl) {
  __shared__ float Bc[16][56];
  const int tid = threadIdx.x;
  const int o0 = blockIdx.x * 16;
  const float c0 = 0.5f * alphas[0], c1 = 0.5f * alphas[1], c2 = 0.5f * alphas[2];
  for (int t = tid; t < 16 * 56; t += 256) {
    int oi = t / 56, r = t % 56, o = o0 + oi;
    float v;
    if (r < 8)
      v = c0 * B8[o * 8 + r];
    else if (r < 24)
      v = c1 * B16[o * 16 + (r - 8)];
    else
      v = c2 * B32[o * 32 + (r - 24)];
    Bc[oi][r] = v;
  }
  __syncthreads();
  for (int c = 0; c < 16; ++c) {
    const int d = c * 256 + tid;
    float a[56];
#pragma unroll
    for (int r = 0; r < 8; ++r) a[r] = A8[r * 4096 + d];
#pragma unroll
    for (int r = 0; r < 16; ++r) a[8 + r] = A16[r * 4096 + d];
#pragma unroll
    for (int r = 0; r < 32; ++r) a[24 + r] = A32[r * 4096 + d];
#pragma unroll 4
    for (int oi = 0; oi < 16; ++oi) {
      float w = W[(size_t)(o0 + oi) * 4096 + d];
#pragma unroll
      for (int r = 0; r < 56; ++r) w = fmaf(Bc[oi][r], a[r], w);
      unsigned short h = bf16_rne(w);
      Wh[(size_t)(o0 + oi) * 4096 + d] = h;
      Wl[(size_t)(o0 + oi) * 4096 + d] = bf16_rne(w - bf16_to_f(h));
    }
  }
}

// ---------------- kernel 3: 3-pass split-bf16 GEMM ----------------
// C[8192][4096] = xh@Wh^T + xh@Wl^T + xl@Wh^T
// BM=BN=128, BK=64. 4 waves (2x2), each 64x64 out = 4x4 frags of 16x16.
// LDS tiles [128][64] bf16, XOR-swizzled: byte ^= ((row&7)<<4).
// Staged via global_load_lds w16 with pre-swizzled global source (rule #21).
__global__ __launch_bounds__(256, 3) void gemm3(const unsigned short* __restrict__ Xh,
                                                const unsigned short* __restrict__ Xl,
                                                const unsigned short* __restrict__ Wh,
                                                const unsigned short* __restrict__ Wl,
                                                float* __restrict__ C) {
  __shared__ __align__(16) unsigned short As[128 * 64];  // 16 KB
  __shared__ __align__(16) unsigned short Bs[128 * 64];  // 16 KB

  const int tid = threadIdx.x;
  const int lane = tid & 63;
  const int wid = tid >> 6;
  const int wm = wid >> 1, wn = wid & 1;
  const int m0 = blockIdx.y * 128;
  const int n0 = blockIdx.x * 128;

  // staging geometry: wave wid covers bytes [wid*4096, +4096), inst j covers 1024B
  // s = wid*4096 + j*1024 + lane*16 ; row = s>>7 ; phys slot = (s>>4)&7
  const int srow_base = wid * 32 + (lane >> 3);       // + j*8
  const int lslot = (lane & 7) ^ (lane >> 3);          // logical 16B slot (pre-swizzled src)

  f32x4 acc[4][4];
#pragma unroll
  for (int mi = 0; mi < 4; ++mi)
#pragma unroll
    for (int ni = 0; ni < 4; ++ni) acc[mi][ni] = (f32x4){0.f, 0.f, 0.f, 0.f};

  for (int pass = 0; pass < 3; ++pass) {
    const unsigned short* Ap = (pass == 2) ? Xl : Xh;
    const unsigned short* Bp = (pass == 1) ? Wl : Wh;
    for (int kt = 0; kt < 64; ++kt) {
      const int k0 = kt * 64;
      __syncthreads();  // previous tile's compute done
#pragma unroll
      for (int j = 0; j < 4; ++j) {
        const int row = srow_base + j * 8;
        const size_t ga = (size_t)(m0 + row) * 4096 + k0 + lslot * 8;
        GLOBAL_LOAD_LDS16(Ap + ga, (char*)As + wid * 4096 + j * 1024);
        const size_t gb = (size_t)(n0 + row) * 4096 + k0 + lslot * 8;
        GLOBAL_LOAD_LDS16(Bp + gb, (char*)Bs + wid * 4096 + j * 1024);
      }
      __syncthreads();  // staging drained (vmcnt(0) implied)
#pragma unroll
      for (int ks = 0; ks < 2; ++ks) {
        const int kk = ks * 32 + (lane >> 4) * 8;  // element offset within row
        bf16x8 a[4], b[4];
#pragma unroll
        for (int mi = 0; mi < 4; ++mi) {
          const int row = wm * 64 + mi * 16 + (lane & 15);
          a[mi] = *(const bf16x8*)&As[row * 64 + (kk ^ ((row & 7) << 3))];
        }
#pragma unroll
        for (int ni = 0; ni < 4; ++ni) {
          const int row = wn * 64 + ni * 16 + (lane & 15);
          b[ni] = *(const bf16x8*)&Bs[row * 64 + (kk ^ ((row & 7) << 3))];
        }
#pragma unroll
        for (int mi = 0; mi < 4; ++mi)
#pragma unroll
          for (int ni = 0; ni < 4; ++ni)
            acc[mi][ni] = __builtin_amdgcn_mfma_f32_16x16x32_bf16(a[mi], b[ni],
                                                                  acc[mi][ni], 0, 0, 0);
      }
    }
  }

  // epilogue: C/D layout col = lane&15, row = (lane>>4)*4 + reg  [m89/m91]
#pragma unroll
  for (int mi = 0; mi < 4; ++mi)
#pragma unroll
    for (int ni = 0; ni < 4; ++ni) {
      const int row = m0 + wm * 64 + mi * 16 + (lane >> 4) * 4;
      const int col = n0 + wn * 64 + ni * 16 + (lane & 15);
      float* cp = C + (size_t)row * 4096 + col;
      cp[0] = acc[mi][ni][0];
      cp[4096] = acc[mi][ni][1];
      cp[2 * 4096] = acc[mi][ni][2];
      cp[3 * 4096] = acc[mi][ni][3];
    }
}

extern "C" void kernel_launch(void* const* d_in, const int* in_sizes, int n_in,
                              void* d_out, int out_size, void* d_ws, size_t ws_size,
                              hipStream_t stream) {
  const float* x = (const float*)d_in[0];
  const float* Wb = (const float*)d_in[1];
  const float* A8 = (const float*)d_in[2];
  const float* B8 = (const float*)d_in[3];
  const float* A16 = (const float*)d_in[4];
  const float* B16 = (const float*)d_in[5];
  const float* A32 = (const float*)d_in[6];
  const float* B32 = (const float*)d_in[7];
  const float* al = (const float*)d_in[8];
  float* out = (float*)d_out;

  char* ws = (char*)d_ws;
  unsigned short* xh = (unsigned short*)(ws);
  unsigned short* xl = (unsigned short*)(ws + 67108864);   // 64 MB
  unsigned short* wh = (unsigned short*)(ws + 134217728);  // 128 MB
  unsigned short* wl = (unsigned short*)(ws + 167772160);  // 160 MB

  split_x<<<16384, 256, 0, stream>>>(x, xh, xl);
  fold_w<<<256, 256, 0, stream>>>(Wb, A8, B8, A16, B16, A32, B32, al, wh, wl);
  gemm3<<<dim3(32, 64), 256, 0, stream>>>(xh, xl, wh, wl, out);
}